// Round 5
// baseline (2225.306 us; speedup 1.0000x reference)
//
#include <hip/hip_runtime.h>
#include <stdint.h>
#include <math.h>

#define R_ 16
#define C_ 256
#define B_ 12
#define E_ 768
#define H_ 12
#define D_ 64
#define TOK (R_*C_*B_)          // 49152

typedef __bf16 bf16x8 __attribute__((ext_vector_type(8)));
typedef float floatx4 __attribute__((ext_vector_type(4)));

__device__ __forceinline__ unsigned short f2bf(float f) {
    union { unsigned int i; float f; } v; v.f = f;
    unsigned int i = v.i;
    return (unsigned short)((i + 0x7fffu + ((i >> 16) & 1u)) >> 16);  // RNE
}
__device__ __forceinline__ bf16x8 cvt8(floatx4 lo, floatx4 hi) {
    bf16x8 r;
    r[0] = (__bf16)lo[0]; r[1] = (__bf16)lo[1]; r[2] = (__bf16)lo[2]; r[3] = (__bf16)lo[3];
    r[4] = (__bf16)hi[0]; r[5] = (__bf16)hi[1]; r[6] = (__bf16)hi[2]; r[7] = (__bf16)hi[3];
    return r;
}

// ---------------------------------------------------------------------------
// 128x128 A*B^T GEMM, per-batch-n variants. d_out is FLOAT32.
// MODE 0: proj q/k:  A = x rows (m*12+n) f32; Bt = W f32; bf16 q_n[m][768]
// MODE 1: scores:    A=q_n, Bt=k_n (bf16, K=rd=1024, col h*64+d), z=h;
//                    f32 out -> probs[(h*12+n)*65536 + i*256 + j]
// MODE 2: PV:        A = probs pair (h,n) f32 (cvt->bf16), K=j=256;
//                    Bt = vt_n[h*1024+rd][j] bf16, z=h;
//                    bf16 out ctx_n[(r*256+i)*768 + h*64 + d]
// MODE 3: proj v:    f32 in, epilogue -> bf16 vt_n[(h*1024 + r*64+d)*256 + j]
// MODE 4: out proj:  A = ctx_n bf16; Bt = Wo f32; f32 out rows (m*12+n)
// ---------------------------------------------------------------------------
template<int MODE>
__global__ __launch_bounds__(256)
void gemm_bt(const void* __restrict__ Ap,
             const void* __restrict__ Btp,
             const float* __restrict__ bias,
             void* __restrict__ Cout,
             int nIdx)
{
    __shared__ __align__(16) unsigned short As[128 * 32];
    __shared__ __align__(16) unsigned short Bs[128 * 32];

    const int K = (MODE == 1) ? 1024 : ((MODE == 2) ? 256 : 768);

    const int tid  = threadIdx.x;
    const int wave = tid >> 6, lane = tid & 63;
    const int quad = lane >> 4, l15 = lane & 15;
    const int wr = wave >> 1, wc = wave & 1;
    const int row0 = blockIdx.y * 128, col0 = blockIdx.x * 128;
    const int hIdx = (MODE == 1 || MODE == 2) ? blockIdx.z : 0;

    const floatx4 zero = {0.f, 0.f, 0.f, 0.f};
    floatx4 acc[4][4];
#pragma unroll
    for (int i = 0; i < 4; ++i)
#pragma unroll
        for (int j = 0; j < 4; ++j) acc[i][j] = zero;

    const int kIters = K >> 5;
    for (int kt = 0; kt < kIters; ++kt) {
        const int k0 = kt << 5;
        bf16x8 ra[2], rbv[2];
#pragma unroll
        for (int it = 0; it < 2; ++it) {
            const int idx = it * 256 + tid;        // 128 rows x 4 k-chunks
            const int row = idx >> 2, ck = idx & 3;
            const int kk = k0 + ck * 8;
            if (MODE == 0 || MODE == 3) {          // f32 x rows (m*12+n), f32 W
                const float* ga = (const float*)Ap
                                  + ((size_t)(row0 + row) * 12 + nIdx) * 768 + kk;
                const float* gb = (const float*)Btp + (size_t)(col0 + row) * 768 + kk;
                ra[it]  = cvt8(((const floatx4*)ga)[0], ((const floatx4*)ga)[1]);
                rbv[it] = cvt8(((const floatx4*)gb)[0], ((const floatx4*)gb)[1]);
            } else if (MODE == 4) {                // bf16 ctx_n, f32 Wo
                const unsigned short* ga = (const unsigned short*)Ap
                                           + (size_t)(row0 + row) * 768 + kk;
                const float* gb = (const float*)Btp + (size_t)(col0 + row) * 768 + kk;
                ra[it]  = *(const bf16x8*)ga;
                rbv[it] = cvt8(((const floatx4*)gb)[0], ((const floatx4*)gb)[1]);
            } else if (MODE == 1) {                // bf16 q_n/k_n, k-dim rd
                const int r = kk >> 6, d = kk & 63;
                ra[it]  = *(const bf16x8*)((const unsigned short*)Ap
                          + ((size_t)r * 256 + row0 + row) * 768 + hIdx * 64 + d);
                rbv[it] = *(const bf16x8*)((const unsigned short*)Btp
                          + ((size_t)r * 256 + col0 + row) * 768 + hIdx * 64 + d);
            } else {                               // MODE 2: f32 probs, bf16 vt_n
                const float* ga = (const float*)Ap
                                  + ((size_t)(hIdx * 12 + nIdx)) * 65536
                                  + (size_t)(row0 + row) * 256 + kk;
                ra[it]  = cvt8(((const floatx4*)ga)[0], ((const floatx4*)ga)[1]);
                rbv[it] = *(const bf16x8*)((const unsigned short*)Btp
                          + ((size_t)hIdx * 1024 + col0 + row) * 256 + kk);
            }
        }
        __syncthreads();   // previous iteration's LDS readers done
#pragma unroll
        for (int it = 0; it < 2; ++it) {
            const int idx = it * 256 + tid;
            *(bf16x8*)(As + (size_t)idx * 8) = ra[it];
            *(bf16x8*)(Bs + (size_t)idx * 8) = rbv[it];
        }
        __syncthreads();   // LDS tiles valid

        bf16x8 af[4], bfr[4];
#pragma unroll
        for (int t = 0; t < 4; ++t) {
            af[t]  = *(const bf16x8*)(As + ((wr * 64 + t * 16 + l15) * 32 + quad * 8));
            bfr[t] = *(const bf16x8*)(Bs + ((wc * 64 + t * 16 + l15) * 32 + quad * 8));
        }
#pragma unroll
        for (int tm = 0; tm < 4; ++tm)
#pragma unroll
            for (int tn = 0; tn < 4; ++tn)
                acc[tm][tn] = __builtin_amdgcn_mfma_f32_16x16x32_bf16(
                    af[tm], bfr[tn], acc[tm][tn], 0, 0, 0);
    }

    // Epilogue. C/D layout: col = lane&15, row = quad*4 + reg.
#pragma unroll
    for (int tm = 0; tm < 4; ++tm) {
        const int rbase = row0 + wr * 64 + tm * 16 + quad * 4;
#pragma unroll
        for (int tn = 0; tn < 4; ++tn) {
            const int cc = col0 + wc * 64 + tn * 16 + l15;
#pragma unroll
            for (int rr = 0; rr < 4; ++rr) {
                float vv = acc[tm][tn][rr];
                const int rowg = rbase + rr;
                if (MODE == 0) {
                    ((unsigned short*)Cout)[(size_t)rowg * 768 + cc] = f2bf(vv + bias[cc]);
                } else if (MODE == 1) {
                    ((float*)Cout)[((size_t)(hIdx * 12 + nIdx)) * 65536
                                   + (size_t)rowg * 256 + cc] = vv * 0.03125f;
                } else if (MODE == 2) {   // ctx_n[(r*256+i)*768 + h*64 + d]
                    ((unsigned short*)Cout)[(((size_t)(cc >> 6)) * 256 + rowg) * 768
                                            + hIdx * 64 + (cc & 63)] = f2bf(vv);
                } else if (MODE == 3) {   // vt_n[(h*1024 + r*64+d)*256 + j]
                    ((unsigned short*)Cout)[(((size_t)(cc >> 6)) * 1024
                                             + (rowg >> 8) * 64 + (cc & 63)) * 256
                                            + (rowg & 255)] = f2bf(vv + bias[cc]);
                } else {                  // MODE 4: f32 out rows (m*12+n)
                    ((float*)Cout)[((size_t)rowg * 12 + nIdx) * 768 + cc] = vv + bias[cc];
                }
            }
        }
    }
}

// ---------------------------------------------------------------------------
// T5 relative-position buckets (f32 op order matches reference)
// ---------------------------------------------------------------------------
__global__ __launch_bounds__(256)
void bucket_kernel(const int* __restrict__ dist, int* __restrict__ buckets)
{
    const int idx = blockIdx.x * 256 + threadIdx.x;
    if (idx >= B_ * C_ * C_) return;
    const int dv = dist[idx];
    const int n = dv < 0 ? -dv : dv;
    int bkt;
    if (n < 16) {
        bkt = n;
    } else {
        const float lg = logf((float)n * 0.0625f);        // log(n/16)
        const float t  = (lg / 8.047189562170502f) * 15.0f;
        bkt = 16 + (int)t;
        if (bkt > 31) bkt = 31;
    }
    buckets[idx] = bkt;
}

// ---------------------------------------------------------------------------
// In-place f32 bias + softmax over j. One wave per row.
// probs[(h*12+n)*256+i][j], f32. attn[h,n,i,j] += rel_bias[bkt(dist[h,i,j]), n]
// ---------------------------------------------------------------------------
__global__ __launch_bounds__(256)
void softmax_bias(float* __restrict__ probs,
                  const int* __restrict__ buckets,
                  const float* __restrict__ rb)
{
    const int wave = threadIdx.x >> 6, lane = threadIdx.x & 63;
    const int rowid = blockIdx.x * 4 + wave;     // [0, 36864)
    const int p = rowid >> 8;
    const int i = rowid & 255;
    const int a = p / 12, b = p - a * 12;        // a = h, b = n
    float* prow = probs + (size_t)rowid * 256;
    const int* brow = buckets + ((size_t)a * 256 + i) * 256;

    float vals[4];
    float mx = -3.4e38f;
#pragma unroll
    for (int t = 0; t < 4; ++t) {
        const int j = t * 64 + lane;
        vals[t] = prow[j] + rb[brow[j] * 12 + b];
        mx = fmaxf(mx, vals[t]);
    }
#pragma unroll
    for (int off = 32; off > 0; off >>= 1) mx = fmaxf(mx, __shfl_xor(mx, off, 64));
    float sum = 0.f;
#pragma unroll
    for (int t = 0; t < 4; ++t) { vals[t] = expf(vals[t] - mx); sum += vals[t]; }
#pragma unroll
    for (int off = 32; off > 0; off >>= 1) sum += __shfl_xor(sum, off, 64);
    const float inv = 1.f / sum;
#pragma unroll
    for (int t = 0; t < 4; ++t) prow[t * 64 + lane] = vals[t] * inv;
}

// ---------------------------------------------------------------------------
// Memory plan: d_ws total 28,311,552 B (27 MB). d_out (FLOAT32) never scratch.
//   buckets : ws +         0   (3,145,728 B)
//   q_n     : ws + 3,145,728   (6,291,456 B)   [4096 tok x 768] bf16
//   k_n     : ws + 9,437,184   (6,291,456 B)
//   vt_n    : ws + 15,728,640  (6,291,456 B)   [12h x 1024rd x 256j] bf16
//   ctx_n   : ws + 22,020,096  (6,291,456 B)
// ---------------------------------------------------------------------------
extern "C" void kernel_launch(void* const* d_in, const int* in_sizes, int n_in,
                              void* d_out, int out_size, void* d_ws, size_t ws_size,
                              hipStream_t stream)
{
    const float* x    = (const float*)d_in[0];
    const int*   dist = (const int*)d_in[1];
    const float* Wq   = (const float*)d_in[2];
    const float* bq   = (const float*)d_in[3];
    const float* Wk   = (const float*)d_in[4];
    const float* bk   = (const float*)d_in[5];
    const float* Wv   = (const float*)d_in[6];
    const float* bv   = (const float*)d_in[7];
    const float* Wo   = (const float*)d_in[8];
    const float* bo   = (const float*)d_in[9];
    const float* rb   = (const float*)d_in[10];

    float* outp  = (float*)d_out;
    float* probs = (float*)d_out + (size_t)TOK * E_;   // f32 element 37748736

    char* ws = (char*)d_ws;
    int* buckets         = (int*)(ws);
    unsigned short* q_n  = (unsigned short*)(ws + 3145728);
    unsigned short* k_n  = (unsigned short*)(ws + 9437184);
    unsigned short* vt_n = (unsigned short*)(ws + 15728640);
    unsigned short* ctx_n= (unsigned short*)(ws + 22020096);

    dim3 blk(256);

    bucket_kernel<<<dim3(3072), blk, 0, stream>>>(dist, buckets);

    // Phase 1: per-n q/k projection + scores -> f32 probs region of d_out
    for (int n = 0; n < 12; ++n) {
        gemm_bt<0><<<dim3(6, 32), blk, 0, stream>>>(x, Wq, bq, q_n, n);
        gemm_bt<0><<<dim3(6, 32), blk, 0, stream>>>(x, Wk, bk, k_n, n);
        gemm_bt<1><<<dim3(2, 2, 12), blk, 0, stream>>>(q_n, k_n, nullptr, probs, n);
    }

    // Phase 2: f32 bias + softmax in place (all pairs)
    softmax_bias<<<dim3(9216), blk, 0, stream>>>(probs, buckets, rb);

    // Phase 3: per-n v projection (transposed), PV, out projection
    for (int n = 0; n < 12; ++n) {
        gemm_bt<3><<<dim3(6, 32), blk, 0, stream>>>(x, Wv, bv, vt_n, n);
        gemm_bt<2><<<dim3(8, 2, 12), blk, 0, stream>>>(probs, vt_n, nullptr, ctx_n, n);
        gemm_bt<4><<<dim3(6, 32), blk, 0, stream>>>(ctx_n, Wo, bo, outp, n);
    }
}